// Round 6
// baseline (211.399 us; speedup 1.0000x reference)
//
#include <hip/hip_runtime.h>

#define N_NODES   100000
#define N_EDGES   600000
#define D_FEAT    128
#define N_CLASSES 40

#define NPAD      100352            // N_NODES padded to 1024 multiple
#define SCAN_NBLK (NPAD / 1024)     // 98

// ================= CSR build =================

__global__ void k_zero(int4* __restrict__ deg4) {
    int i = blockIdx.x * blockDim.x + threadIdx.x;
    if (i < NPAD / 4) deg4[i] = make_int4(0, 0, 0, 0);
}

__global__ void k_count(const int* __restrict__ edst, int* __restrict__ deg) {
    int e = blockIdx.x * blockDim.x + threadIdx.x;
    if (e < N_EDGES) atomicAdd(&deg[edst[e]], 1);
}

// phase 1: per-block exclusive scan (1024 elems/block), local prefixes -> row_ptr
__global__ __launch_bounds__(256) void k_scan1(const int* __restrict__ deg,
                                               int* __restrict__ row_ptr,
                                               int* __restrict__ blksum) {
    __shared__ int wsum[4];
    int t = threadIdx.x;
    int lane = t & 63, w = t >> 6;
    int base = blockIdx.x * 1024 + t * 4;
    int4 v = *(const int4*)(deg + base);
    int s0 = v.x, s1 = s0 + v.y, s2 = s1 + v.z, s3 = s2 + v.w;
    int inc = s3;
#pragma unroll
    for (int d = 1; d < 64; d <<= 1) {
        int y = __shfl_up(inc, d, 64);
        if (lane >= d) inc += y;
    }
    if (lane == 63) wsum[w] = inc;
    __syncthreads();
    int woff = 0;
#pragma unroll
    for (int j = 0; j < 3; ++j) woff += (j < w) ? wsum[j] : 0;
    int texcl = woff + inc - s3;
    int4 o;
    o.x = texcl;
    o.y = texcl + s0;
    o.z = texcl + s1;
    o.w = texcl + s2;
    *(int4*)(row_ptr + base) = o;
    if (t == 255) blksum[blockIdx.x] = woff + inc;   // block total
}

// phase 2: add block offsets in place; emit cursor + dinv
__global__ __launch_bounds__(256) void k_scan2(const int* __restrict__ deg,
                                               int* __restrict__ row_ptr,
                                               int* __restrict__ cursor,
                                               float* __restrict__ dinv,
                                               const int* __restrict__ blksum) {
    __shared__ int s[SCAN_NBLK];
    int t = threadIdx.x;
    int blk = blockIdx.x;
    if (t < SCAN_NBLK) s[t] = blksum[t];
    __syncthreads();
    int off = 0;
    for (int j = 0; j < blk; ++j) off += s[j];
    int base = blk * 1024 + t * 4;
    int4 v = *(int4*)(row_ptr + base);
    v.x += off; v.y += off; v.z += off; v.w += off;
    *(int4*)(row_ptr + base) = v;
    *(int4*)(cursor + base) = v;
    int4 d = *(const int4*)(deg + base);
    float4 di;
    di.x = rsqrtf((float)(d.x + 1));
    di.y = rsqrtf((float)(d.y + 1));
    di.z = rsqrtf((float)(d.z + 1));
    di.w = rsqrtf((float)(d.w + 1));
    *(float4*)(dinv + base) = di;
    // row_ptr[N_NODES] = 600000 falls out of the scan (deg padding is zero)
}

__global__ void k_fill(const int* __restrict__ esrc, const int* __restrict__ edst,
                       int* __restrict__ cursor, int* __restrict__ csr_src) {
    int e = blockIdx.x * blockDim.x + threadIdx.x;
    if (e < N_EDGES) {
        int d = edst[e];
        int pos = atomicAdd(&cursor[d], 1);
        csr_src[pos] = esrc[e];
    }
}

// ================= u0 = (x @ W^T) * dinv[node] =================
// 128 threads/block = 32 quads; each quad (4 threads, 10 classes each)
// computes 4 consecutive nodes. No LDS: W is 20 KB and stays L1/L2-hot;
// within a quad the W float4 addresses coincide across the 16 quads of a
// wave (4 unique lines/instr -> coalesced broadcast). Grid 782 blocks.

__global__ __launch_bounds__(128) void k_gemm(const float* __restrict__ x,
                                              const float* __restrict__ W,
                                              const float* __restrict__ dinv,
                                              float* __restrict__ y) {
    int t = threadIdx.x;
    int quad = t >> 2;                      // 0..31
    int sub  = t & 3;
    int c0   = sub * 10;
    int n0   = blockIdx.x * 128 + quad * 4; // N_NODES % 4 == 0: quad all-or-nothing
    if (n0 >= N_NODES) return;

    const float4* xp = (const float4*)(x + (size_t)n0 * D_FEAT);  // rows n0..n0+3
    const float4* wp = (const float4*)W + (size_t)c0 * 32;        // rows c0..c0+9

    float acc[4][10];
#pragma unroll
    for (int k = 0; k < 4; ++k)
#pragma unroll
        for (int j = 0; j < 10; ++j) acc[k][j] = 0.f;

    for (int d4 = 0; d4 < D_FEAT / 4; ++d4) {
        float4 x0 = xp[d4];
        float4 x1 = xp[32 + d4];
        float4 x2 = xp[64 + d4];
        float4 x3 = xp[96 + d4];
#pragma unroll
        for (int j = 0; j < 10; ++j) {
            float4 wv = wp[j * 32 + d4];
            acc[0][j] += x0.x * wv.x + x0.y * wv.y + x0.z * wv.z + x0.w * wv.w;
            acc[1][j] += x1.x * wv.x + x1.y * wv.y + x1.z * wv.z + x1.w * wv.w;
            acc[2][j] += x2.x * wv.x + x2.y * wv.y + x2.z * wv.z + x2.w * wv.w;
            acc[3][j] += x3.x * wv.x + x3.y * wv.y + x3.z * wv.z + x3.w * wv.w;
        }
    }

#pragma unroll
    for (int k = 0; k < 4; ++k) {
        float di = dinv[n0 + k];
        float* o = y + (size_t)(n0 + k) * N_CLASSES + c0;
#pragma unroll
        for (int j = 0; j < 10; ++j) o[j] = acc[k][j] * di;
    }
}

// ================= CSR gather propagation on u (4 threads/node) =================
// u_out[d] = dinv[d]^2 * ( u_in[d] + sum_{s in N(d)} u_in[s] )
// thread role: sub = feature half (bit0), par = edge parity (bit1).
// parity loop unrolled x2: two source rows (10 float4 loads) in flight.

__global__ __launch_bounds__(256) void k_gather(const float* __restrict__ yin,
                                                float* __restrict__ yout,
                                                const float* __restrict__ dinv,
                                                const int* __restrict__ row_ptr,
                                                const int* __restrict__ csr_src) {
    int t = blockIdx.x * blockDim.x + threadIdx.x;
    int i = t >> 2;
    if (i >= N_NODES) return;
    int sub = t & 1;
    int par = (t >> 1) & 1;
    const float4* yb = (const float4*)yin;

    float4 a0, a1, a2, a3, a4;
    if (par == 0) {
        const float4* self = yb + (size_t)i * 10 + sub * 5;
        a0 = self[0]; a1 = self[1]; a2 = self[2]; a3 = self[3]; a4 = self[4];
    } else {
        a0 = a1 = a2 = a3 = a4 = make_float4(0.f, 0.f, 0.f, 0.f);
    }

    int e = row_ptr[i] + par, end = row_ptr[i + 1];
    for (; e + 2 < end; e += 4) {
        int s0 = csr_src[e], s1 = csr_src[e + 2];
        const float4* p0 = yb + (size_t)s0 * 10 + sub * 5;
        const float4* p1 = yb + (size_t)s1 * 10 + sub * 5;
        float4 v00 = p0[0], v01 = p0[1], v02 = p0[2], v03 = p0[3], v04 = p0[4];
        float4 v10 = p1[0], v11 = p1[1], v12 = p1[2], v13 = p1[3], v14 = p1[4];
        a0.x += v00.x + v10.x; a0.y += v00.y + v10.y; a0.z += v00.z + v10.z; a0.w += v00.w + v10.w;
        a1.x += v01.x + v11.x; a1.y += v01.y + v11.y; a1.z += v01.z + v11.z; a1.w += v01.w + v11.w;
        a2.x += v02.x + v12.x; a2.y += v02.y + v12.y; a2.z += v02.z + v12.z; a2.w += v02.w + v12.w;
        a3.x += v03.x + v13.x; a3.y += v03.y + v13.y; a3.z += v03.z + v13.z; a3.w += v03.w + v13.w;
        a4.x += v04.x + v14.x; a4.y += v04.y + v14.y; a4.z += v04.z + v14.z; a4.w += v04.w + v14.w;
    }
    if (e < end) {
        int s = csr_src[e];
        const float4* p = yb + (size_t)s * 10 + sub * 5;
        float4 v0 = p[0], v1 = p[1], v2 = p[2], v3 = p[3], v4 = p[4];
        a0.x += v0.x; a0.y += v0.y; a0.z += v0.z; a0.w += v0.w;
        a1.x += v1.x; a1.y += v1.y; a1.z += v1.z; a1.w += v1.w;
        a2.x += v2.x; a2.y += v2.y; a2.z += v2.z; a2.w += v2.w;
        a3.x += v3.x; a3.y += v3.y; a3.z += v3.z; a3.w += v3.w;
        a4.x += v4.x; a4.y += v4.y; a4.z += v4.z; a4.w += v4.w;
    }

    // combine edge-parity partial sums (lanes differ in bit 1)
    a0.x += __shfl_xor(a0.x, 2); a0.y += __shfl_xor(a0.y, 2); a0.z += __shfl_xor(a0.z, 2); a0.w += __shfl_xor(a0.w, 2);
    a1.x += __shfl_xor(a1.x, 2); a1.y += __shfl_xor(a1.y, 2); a1.z += __shfl_xor(a1.z, 2); a1.w += __shfl_xor(a1.w, 2);
    a2.x += __shfl_xor(a2.x, 2); a2.y += __shfl_xor(a2.y, 2); a2.z += __shfl_xor(a2.z, 2); a2.w += __shfl_xor(a2.w, 2);
    a3.x += __shfl_xor(a3.x, 2); a3.y += __shfl_xor(a3.y, 2); a3.z += __shfl_xor(a3.z, 2); a3.w += __shfl_xor(a3.w, 2);
    a4.x += __shfl_xor(a4.x, 2); a4.y += __shfl_xor(a4.y, 2); a4.z += __shfl_xor(a4.z, 2); a4.w += __shfl_xor(a4.w, 2);

    if (par == 0) {
        float di = dinv[i];
        float s2 = di * di;
        float4* o = (float4*)yout + (size_t)i * 10 + sub * 5;
        o[0] = make_float4(a0.x * s2, a0.y * s2, a0.z * s2, a0.w * s2);
        o[1] = make_float4(a1.x * s2, a1.y * s2, a1.z * s2, a1.w * s2);
        o[2] = make_float4(a2.x * s2, a2.y * s2, a2.z * s2, a2.w * s2);
        o[3] = make_float4(a3.x * s2, a3.y * s2, a3.z * s2, a3.w * s2);
        o[4] = make_float4(a4.x * s2, a4.y * s2, a4.z * s2, a4.w * s2);
    }
}

// final round: logits = dinv[d]*v + b, then log_softmax
__global__ __launch_bounds__(256) void k_gather_out(const float* __restrict__ yin,
                                                    float* __restrict__ out,
                                                    const float* __restrict__ dinv,
                                                    const int* __restrict__ row_ptr,
                                                    const int* __restrict__ csr_src,
                                                    const float* __restrict__ bias) {
    int t = blockIdx.x * blockDim.x + threadIdx.x;
    int i = t >> 2;
    if (i >= N_NODES) return;
    int sub = t & 1;
    int par = (t >> 1) & 1;
    const float4* yb = (const float4*)yin;

    float4 a0, a1, a2, a3, a4;
    if (par == 0) {
        const float4* self = yb + (size_t)i * 10 + sub * 5;
        a0 = self[0]; a1 = self[1]; a2 = self[2]; a3 = self[3]; a4 = self[4];
    } else {
        a0 = a1 = a2 = a3 = a4 = make_float4(0.f, 0.f, 0.f, 0.f);
    }

    int e = row_ptr[i] + par, end = row_ptr[i + 1];
    for (; e + 2 < end; e += 4) {
        int s0 = csr_src[e], s1 = csr_src[e + 2];
        const float4* p0 = yb + (size_t)s0 * 10 + sub * 5;
        const float4* p1 = yb + (size_t)s1 * 10 + sub * 5;
        float4 v00 = p0[0], v01 = p0[1], v02 = p0[2], v03 = p0[3], v04 = p0[4];
        float4 v10 = p1[0], v11 = p1[1], v12 = p1[2], v13 = p1[3], v14 = p1[4];
        a0.x += v00.x + v10.x; a0.y += v00.y + v10.y; a0.z += v00.z + v10.z; a0.w += v00.w + v10.w;
        a1.x += v01.x + v11.x; a1.y += v01.y + v11.y; a1.z += v01.z + v11.z; a1.w += v01.w + v11.w;
        a2.x += v02.x + v12.x; a2.y += v02.y + v12.y; a2.z += v02.z + v12.z; a2.w += v02.w + v12.w;
        a3.x += v03.x + v13.x; a3.y += v03.y + v13.y; a3.z += v03.z + v13.z; a3.w += v03.w + v13.w;
        a4.x += v04.x + v14.x; a4.y += v04.y + v14.y; a4.z += v04.z + v14.z; a4.w += v04.w + v14.w;
    }
    if (e < end) {
        int s = csr_src[e];
        const float4* p = yb + (size_t)s * 10 + sub * 5;
        float4 v0 = p[0], v1 = p[1], v2 = p[2], v3 = p[3], v4 = p[4];
        a0.x += v0.x; a0.y += v0.y; a0.z += v0.z; a0.w += v0.w;
        a1.x += v1.x; a1.y += v1.y; a1.z += v1.z; a1.w += v1.w;
        a2.x += v2.x; a2.y += v2.y; a2.z += v2.z; a2.w += v2.w;
        a3.x += v3.x; a3.y += v3.y; a3.z += v3.z; a3.w += v3.w;
        a4.x += v4.x; a4.y += v4.y; a4.z += v4.z; a4.w += v4.w;
    }

    a0.x += __shfl_xor(a0.x, 2); a0.y += __shfl_xor(a0.y, 2); a0.z += __shfl_xor(a0.z, 2); a0.w += __shfl_xor(a0.w, 2);
    a1.x += __shfl_xor(a1.x, 2); a1.y += __shfl_xor(a1.y, 2); a1.z += __shfl_xor(a1.z, 2); a1.w += __shfl_xor(a1.w, 2);
    a2.x += __shfl_xor(a2.x, 2); a2.y += __shfl_xor(a2.y, 2); a2.z += __shfl_xor(a2.z, 2); a2.w += __shfl_xor(a2.w, 2);
    a3.x += __shfl_xor(a3.x, 2); a3.y += __shfl_xor(a3.y, 2); a3.z += __shfl_xor(a3.z, 2); a3.w += __shfl_xor(a3.w, 2);
    a4.x += __shfl_xor(a4.x, 2); a4.y += __shfl_xor(a4.y, 2); a4.z += __shfl_xor(a4.z, 2); a4.w += __shfl_xor(a4.w, 2);

    float di = dinv[i];
    const float4* b4 = (const float4*)bias + sub * 5;
    float4 av[5] = {a0, a1, a2, a3, a4};
    float4 l[5];
    float m = -INFINITY;
#pragma unroll
    for (int r = 0; r < 5; ++r) {
        float4 b = b4[r];
        l[r].x = av[r].x * di + b.x;
        l[r].y = av[r].y * di + b.y;
        l[r].z = av[r].z * di + b.z;
        l[r].w = av[r].w * di + b.w;
        m = fmaxf(m, fmaxf(fmaxf(l[r].x, l[r].y), fmaxf(l[r].z, l[r].w)));
    }
    m = fmaxf(m, __shfl_xor(m, 1));     // combine feature halves (bit 0)
    float s = 0.f;
#pragma unroll
    for (int r = 0; r < 5; ++r) {
        s += __expf(l[r].x - m) + __expf(l[r].y - m)
           + __expf(l[r].z - m) + __expf(l[r].w - m);
    }
    s += __shfl_xor(s, 1);
    float lse = __logf(s) + m;

    if (par == 0) {
        float4* o = (float4*)out + (size_t)i * 10 + sub * 5;
#pragma unroll
        for (int r = 0; r < 5; ++r) {
            o[r] = make_float4(l[r].x - lse, l[r].y - lse, l[r].z - lse, l[r].w - lse);
        }
    }
}

// ================= launch =================

extern "C" void kernel_launch(void* const* d_in, const int* in_sizes, int n_in,
                              void* d_out, int out_size, void* d_ws, size_t ws_size,
                              hipStream_t stream) {
    const float* x   = (const float*)d_in[0];
    const int*   ei  = (const int*)d_in[1];
    const float* W   = (const float*)d_in[2];
    const float* b   = (const float*)d_in[3];
    float*       out = (float*)d_out;

    const int* esrc = ei;
    const int* edst = ei + N_EDGES;

    // workspace layout (4-byte elems, 16B-aligned sections)
    int*   deg     = (int*)d_ws;                       // NPAD
    int*   row_ptr = deg + NPAD;                       // NPAD (covers N_NODES+1)
    int*   cursor  = row_ptr + NPAD;                   // NPAD
    int*   blksum  = cursor + NPAD;                    // 128
    int*   csr_src = blksum + 128;                     // 600064
    float* dinv    = (float*)(csr_src + 600064);       // NPAD
    float* u0      = dinv + NPAD;                      // 4,000,000
    float* u1      = u0 + (size_t)N_NODES * N_CLASSES; // 4,000,000

    const int B = 256;
    const int gE = (N_EDGES + B - 1) / B;              // 2344
    const int gG = (4 * N_NODES + B - 1) / B;          // 1563 (4 threads/node)

    k_zero <<<(NPAD / 4 + B - 1) / B, B, 0, stream>>>((int4*)deg);
    k_count<<<gE, B, 0, stream>>>(edst, deg);
    k_scan1<<<SCAN_NBLK, B, 0, stream>>>(deg, row_ptr, blksum);
    k_scan2<<<SCAN_NBLK, B, 0, stream>>>(deg, row_ptr, cursor, dinv, blksum);
    k_fill <<<gE, B, 0, stream>>>(esrc, edst, cursor, csr_src);

    k_gemm<<<(N_NODES + 127) / 128, 128, 0, stream>>>(x, W, dinv, u0);

    k_gather    <<<gG, B, 0, stream>>>(u0, u1, dinv, row_ptr, csr_src);
    k_gather_out<<<gG, B, 0, stream>>>(u1, out, dinv, row_ptr, csr_src, b);
}

// Round 7
// 158.493 us; speedup vs baseline: 1.3338x; 1.3338x over previous
//
#include <hip/hip_runtime.h>

#define N_NODES   100000
#define N_EDGES   600000
#define D_FEAT    128
#define N_CLASSES 40

#define NPAD      100352            // N_NODES padded to 1024 multiple
#define SCAN_NBLK (NPAD / 1024)     // 98

// ================= CSR build =================

__global__ void k_zero(int4* __restrict__ deg4) {
    int i = blockIdx.x * blockDim.x + threadIdx.x;
    if (i < NPAD / 4) deg4[i] = make_int4(0, 0, 0, 0);
}

__global__ void k_count(const int* __restrict__ edst, int* __restrict__ deg) {
    int e = blockIdx.x * blockDim.x + threadIdx.x;
    if (e < N_EDGES) atomicAdd(&deg[edst[e]], 1);
}

// phase 1: per-block exclusive scan (1024 elems/block), local prefixes -> row_ptr
__global__ __launch_bounds__(256) void k_scan1(const int* __restrict__ deg,
                                               int* __restrict__ row_ptr,
                                               int* __restrict__ blksum) {
    __shared__ int wsum[4];
    int t = threadIdx.x;
    int lane = t & 63, w = t >> 6;
    int base = blockIdx.x * 1024 + t * 4;
    int4 v = *(const int4*)(deg + base);
    int s0 = v.x, s1 = s0 + v.y, s2 = s1 + v.z, s3 = s2 + v.w;
    int inc = s3;
#pragma unroll
    for (int d = 1; d < 64; d <<= 1) {
        int y = __shfl_up(inc, d, 64);
        if (lane >= d) inc += y;
    }
    if (lane == 63) wsum[w] = inc;
    __syncthreads();
    int woff = 0;
#pragma unroll
    for (int j = 0; j < 3; ++j) woff += (j < w) ? wsum[j] : 0;
    int texcl = woff + inc - s3;
    int4 o;
    o.x = texcl;
    o.y = texcl + s0;
    o.z = texcl + s1;
    o.w = texcl + s2;
    *(int4*)(row_ptr + base) = o;
    if (t == 255) blksum[blockIdx.x] = woff + inc;   // block total
}

// phase 2: add block offsets in place; emit cursor + dinv
__global__ __launch_bounds__(256) void k_scan2(const int* __restrict__ deg,
                                               int* __restrict__ row_ptr,
                                               int* __restrict__ cursor,
                                               float* __restrict__ dinv,
                                               const int* __restrict__ blksum) {
    __shared__ int s[SCAN_NBLK];
    int t = threadIdx.x;
    int blk = blockIdx.x;
    if (t < SCAN_NBLK) s[t] = blksum[t];
    __syncthreads();
    int off = 0;
    for (int j = 0; j < blk; ++j) off += s[j];
    int base = blk * 1024 + t * 4;
    int4 v = *(int4*)(row_ptr + base);
    v.x += off; v.y += off; v.z += off; v.w += off;
    *(int4*)(row_ptr + base) = v;
    *(int4*)(cursor + base) = v;
    int4 d = *(const int4*)(deg + base);
    float4 di;
    di.x = rsqrtf((float)(d.x + 1));
    di.y = rsqrtf((float)(d.y + 1));
    di.z = rsqrtf((float)(d.z + 1));
    di.w = rsqrtf((float)(d.w + 1));
    *(float4*)(dinv + base) = di;
    // row_ptr[N_NODES] = 600000 falls out of the scan (deg padding is zero)
}

__global__ void k_fill(const int* __restrict__ esrc, const int* __restrict__ edst,
                       int* __restrict__ cursor, int* __restrict__ csr_src) {
    int e = blockIdx.x * blockDim.x + threadIdx.x;
    if (e < N_EDGES) {
        int d = edst[e];
        int pos = atomicAdd(&cursor[d], 1);
        csr_src[pos] = esrc[e];
    }
}

// ================= u0 = (x @ W^T) * dinv[node] =================
// 256 threads/block = 64 quads; each quad (4 threads, 10 classes each)
// computes 2 consecutive nodes -> 128 nodes/block, 782 blocks (~3/CU).
// Per d4-iter/thread: 10 LDS b128 reads feed 80 FMAs (VALU-limited, not LDS).
// W rows at stride 132 floats -> sub-rows hit banks {0,8,16,24}: conflict-free.

#define WROW 132

__global__ __launch_bounds__(256) void k_gemm(const float* __restrict__ x,
                                              const float* __restrict__ W,
                                              const float* __restrict__ dinv,
                                              float* __restrict__ y) {
    __shared__ float Wl[N_CLASSES][WROW];
    int t = threadIdx.x;

    for (int f = t; f < N_CLASSES * (D_FEAT / 4); f += 256) {
        int c = f >> 5, d4 = f & 31;
        float4 w = ((const float4*)W)[f];
        *(float4*)&Wl[c][d4 * 4] = w;
    }
    __syncthreads();

    int quad = t >> 2;                      // 0..63
    int sub  = t & 3;
    int c0   = sub * 10;
    int n0   = blockIdx.x * 128 + quad * 2; // N_NODES % 2 == 0: pair all-or-nothing
    if (n0 >= N_NODES) return;

    const float4* xp = (const float4*)(x + (size_t)n0 * D_FEAT);  // rows n0, n0+1

    float acc[2][10];
#pragma unroll
    for (int k = 0; k < 2; ++k)
#pragma unroll
        for (int j = 0; j < 10; ++j) acc[k][j] = 0.f;

    for (int d4 = 0; d4 < D_FEAT / 4; ++d4) {
        float4 x0 = xp[d4];
        float4 x1 = xp[32 + d4];
#pragma unroll
        for (int j = 0; j < 10; ++j) {
            float4 wv = *(const float4*)&Wl[c0 + j][d4 * 4];
            acc[0][j] += x0.x * wv.x + x0.y * wv.y + x0.z * wv.z + x0.w * wv.w;
            acc[1][j] += x1.x * wv.x + x1.y * wv.y + x1.z * wv.z + x1.w * wv.w;
        }
    }

#pragma unroll
    for (int k = 0; k < 2; ++k) {
        float di = dinv[n0 + k];
        float* o = y + (size_t)(n0 + k) * N_CLASSES + c0;
#pragma unroll
        for (int j = 0; j < 10; ++j) o[j] = acc[k][j] * di;
    }
}

// ================= CSR gather propagation on u (4 threads/node) =================
// u_out[d] = dinv[d]^2 * ( u_in[d] + sum_{s in N(d)} u_in[s] )
// thread role: sub = feature half (bit0), par = edge parity (bit1).
// parity loop unrolled x2: two source rows (10 float4 loads) in flight.

__global__ __launch_bounds__(256) void k_gather(const float* __restrict__ yin,
                                                float* __restrict__ yout,
                                                const float* __restrict__ dinv,
                                                const int* __restrict__ row_ptr,
                                                const int* __restrict__ csr_src) {
    int t = blockIdx.x * blockDim.x + threadIdx.x;
    int i = t >> 2;
    if (i >= N_NODES) return;
    int sub = t & 1;
    int par = (t >> 1) & 1;
    const float4* yb = (const float4*)yin;

    float4 a0, a1, a2, a3, a4;
    if (par == 0) {
        const float4* self = yb + (size_t)i * 10 + sub * 5;
        a0 = self[0]; a1 = self[1]; a2 = self[2]; a3 = self[3]; a4 = self[4];
    } else {
        a0 = a1 = a2 = a3 = a4 = make_float4(0.f, 0.f, 0.f, 0.f);
    }

    int e = row_ptr[i] + par, end = row_ptr[i + 1];
    for (; e + 2 < end; e += 4) {
        int s0 = csr_src[e], s1 = csr_src[e + 2];
        const float4* p0 = yb + (size_t)s0 * 10 + sub * 5;
        const float4* p1 = yb + (size_t)s1 * 10 + sub * 5;
        float4 v00 = p0[0], v01 = p0[1], v02 = p0[2], v03 = p0[3], v04 = p0[4];
        float4 v10 = p1[0], v11 = p1[1], v12 = p1[2], v13 = p1[3], v14 = p1[4];
        a0.x += v00.x + v10.x; a0.y += v00.y + v10.y; a0.z += v00.z + v10.z; a0.w += v00.w + v10.w;
        a1.x += v01.x + v11.x; a1.y += v01.y + v11.y; a1.z += v01.z + v11.z; a1.w += v01.w + v11.w;
        a2.x += v02.x + v12.x; a2.y += v02.y + v12.y; a2.z += v02.z + v12.z; a2.w += v02.w + v12.w;
        a3.x += v03.x + v13.x; a3.y += v03.y + v13.y; a3.z += v03.z + v13.z; a3.w += v03.w + v13.w;
        a4.x += v04.x + v14.x; a4.y += v04.y + v14.y; a4.z += v04.z + v14.z; a4.w += v04.w + v14.w;
    }
    if (e < end) {
        int s = csr_src[e];
        const float4* p = yb + (size_t)s * 10 + sub * 5;
        float4 v0 = p[0], v1 = p[1], v2 = p[2], v3 = p[3], v4 = p[4];
        a0.x += v0.x; a0.y += v0.y; a0.z += v0.z; a0.w += v0.w;
        a1.x += v1.x; a1.y += v1.y; a1.z += v1.z; a1.w += v1.w;
        a2.x += v2.x; a2.y += v2.y; a2.z += v2.z; a2.w += v2.w;
        a3.x += v3.x; a3.y += v3.y; a3.z += v3.z; a3.w += v3.w;
        a4.x += v4.x; a4.y += v4.y; a4.z += v4.z; a4.w += v4.w;
    }

    // combine edge-parity partial sums (lanes differ in bit 1)
    a0.x += __shfl_xor(a0.x, 2); a0.y += __shfl_xor(a0.y, 2); a0.z += __shfl_xor(a0.z, 2); a0.w += __shfl_xor(a0.w, 2);
    a1.x += __shfl_xor(a1.x, 2); a1.y += __shfl_xor(a1.y, 2); a1.z += __shfl_xor(a1.z, 2); a1.w += __shfl_xor(a1.w, 2);
    a2.x += __shfl_xor(a2.x, 2); a2.y += __shfl_xor(a2.y, 2); a2.z += __shfl_xor(a2.z, 2); a2.w += __shfl_xor(a2.w, 2);
    a3.x += __shfl_xor(a3.x, 2); a3.y += __shfl_xor(a3.y, 2); a3.z += __shfl_xor(a3.z, 2); a3.w += __shfl_xor(a3.w, 2);
    a4.x += __shfl_xor(a4.x, 2); a4.y += __shfl_xor(a4.y, 2); a4.z += __shfl_xor(a4.z, 2); a4.w += __shfl_xor(a4.w, 2);

    if (par == 0) {
        float di = dinv[i];
        float s2 = di * di;
        float4* o = (float4*)yout + (size_t)i * 10 + sub * 5;
        o[0] = make_float4(a0.x * s2, a0.y * s2, a0.z * s2, a0.w * s2);
        o[1] = make_float4(a1.x * s2, a1.y * s2, a1.z * s2, a1.w * s2);
        o[2] = make_float4(a2.x * s2, a2.y * s2, a2.z * s2, a2.w * s2);
        o[3] = make_float4(a3.x * s2, a3.y * s2, a3.z * s2, a3.w * s2);
        o[4] = make_float4(a4.x * s2, a4.y * s2, a4.z * s2, a4.w * s2);
    }
}

// final round: logits = dinv[d]*v + b, then log_softmax
__global__ __launch_bounds__(256) void k_gather_out(const float* __restrict__ yin,
                                                    float* __restrict__ out,
                                                    const float* __restrict__ dinv,
                                                    const int* __restrict__ row_ptr,
                                                    const int* __restrict__ csr_src,
                                                    const float* __restrict__ bias) {
    int t = blockIdx.x * blockDim.x + threadIdx.x;
    int i = t >> 2;
    if (i >= N_NODES) return;
    int sub = t & 1;
    int par = (t >> 1) & 1;
    const float4* yb = (const float4*)yin;

    float4 a0, a1, a2, a3, a4;
    if (par == 0) {
        const float4* self = yb + (size_t)i * 10 + sub * 5;
        a0 = self[0]; a1 = self[1]; a2 = self[2]; a3 = self[3]; a4 = self[4];
    } else {
        a0 = a1 = a2 = a3 = a4 = make_float4(0.f, 0.f, 0.f, 0.f);
    }

    int e = row_ptr[i] + par, end = row_ptr[i + 1];
    for (; e + 2 < end; e += 4) {
        int s0 = csr_src[e], s1 = csr_src[e + 2];
        const float4* p0 = yb + (size_t)s0 * 10 + sub * 5;
        const float4* p1 = yb + (size_t)s1 * 10 + sub * 5;
        float4 v00 = p0[0], v01 = p0[1], v02 = p0[2], v03 = p0[3], v04 = p0[4];
        float4 v10 = p1[0], v11 = p1[1], v12 = p1[2], v13 = p1[3], v14 = p1[4];
        a0.x += v00.x + v10.x; a0.y += v00.y + v10.y; a0.z += v00.z + v10.z; a0.w += v00.w + v10.w;
        a1.x += v01.x + v11.x; a1.y += v01.y + v11.y; a1.z += v01.z + v11.z; a1.w += v01.w + v11.w;
        a2.x += v02.x + v12.x; a2.y += v02.y + v12.y; a2.z += v02.z + v12.z; a2.w += v02.w + v12.w;
        a3.x += v03.x + v13.x; a3.y += v03.y + v13.y; a3.z += v03.z + v13.z; a3.w += v03.w + v13.w;
        a4.x += v04.x + v14.x; a4.y += v04.y + v14.y; a4.z += v04.z + v14.z; a4.w += v04.w + v14.w;
    }
    if (e < end) {
        int s = csr_src[e];
        const float4* p = yb + (size_t)s * 10 + sub * 5;
        float4 v0 = p[0], v1 = p[1], v2 = p[2], v3 = p[3], v4 = p[4];
        a0.x += v0.x; a0.y += v0.y; a0.z += v0.z; a0.w += v0.w;
        a1.x += v1.x; a1.y += v1.y; a1.z += v1.z; a1.w += v1.w;
        a2.x += v2.x; a2.y += v2.y; a2.z += v2.z; a2.w += v2.w;
        a3.x += v3.x; a3.y += v3.y; a3.z += v3.z; a3.w += v3.w;
        a4.x += v4.x; a4.y += v4.y; a4.z += v4.z; a4.w += v4.w;
    }

    a0.x += __shfl_xor(a0.x, 2); a0.y += __shfl_xor(a0.y, 2); a0.z += __shfl_xor(a0.z, 2); a0.w += __shfl_xor(a0.w, 2);
    a1.x += __shfl_xor(a1.x, 2); a1.y += __shfl_xor(a1.y, 2); a1.z += __shfl_xor(a1.z, 2); a1.w += __shfl_xor(a1.w, 2);
    a2.x += __shfl_xor(a2.x, 2); a2.y += __shfl_xor(a2.y, 2); a2.z += __shfl_xor(a2.z, 2); a2.w += __shfl_xor(a2.w, 2);
    a3.x += __shfl_xor(a3.x, 2); a3.y += __shfl_xor(a3.y, 2); a3.z += __shfl_xor(a3.z, 2); a3.w += __shfl_xor(a3.w, 2);
    a4.x += __shfl_xor(a4.x, 2); a4.y += __shfl_xor(a4.y, 2); a4.z += __shfl_xor(a4.z, 2); a4.w += __shfl_xor(a4.w, 2);

    float di = dinv[i];
    const float4* b4 = (const float4*)bias + sub * 5;
    float4 av[5] = {a0, a1, a2, a3, a4};
    float4 l[5];
    float m = -INFINITY;
#pragma unroll
    for (int r = 0; r < 5; ++r) {
        float4 b = b4[r];
        l[r].x = av[r].x * di + b.x;
        l[r].y = av[r].y * di + b.y;
        l[r].z = av[r].z * di + b.z;
        l[r].w = av[r].w * di + b.w;
        m = fmaxf(m, fmaxf(fmaxf(l[r].x, l[r].y), fmaxf(l[r].z, l[r].w)));
    }
    m = fmaxf(m, __shfl_xor(m, 1));     // combine feature halves (bit 0)
    float s = 0.f;
#pragma unroll
    for (int r = 0; r < 5; ++r) {
        s += __expf(l[r].x - m) + __expf(l[r].y - m)
           + __expf(l[r].z - m) + __expf(l[r].w - m);
    }
    s += __shfl_xor(s, 1);
    float lse = __logf(s) + m;

    if (par == 0) {
        float4* o = (float4*)out + (size_t)i * 10 + sub * 5;
#pragma unroll
        for (int r = 0; r < 5; ++r) {
            o[r] = make_float4(l[r].x - lse, l[r].y - lse, l[r].z - lse, l[r].w - lse);
        }
    }
}

// ================= launch =================

extern "C" void kernel_launch(void* const* d_in, const int* in_sizes, int n_in,
                              void* d_out, int out_size, void* d_ws, size_t ws_size,
                              hipStream_t stream) {
    const float* x   = (const float*)d_in[0];
    const int*   ei  = (const int*)d_in[1];
    const float* W   = (const float*)d_in[2];
    const float* b   = (const float*)d_in[3];
    float*       out = (float*)d_out;

    const int* esrc = ei;
    const int* edst = ei + N_EDGES;

    // workspace layout (4-byte elems, 16B-aligned sections)
    int*   deg     = (int*)d_ws;                       // NPAD
    int*   row_ptr = deg + NPAD;                       // NPAD (covers N_NODES+1)
    int*   cursor  = row_ptr + NPAD;                   // NPAD
    int*   blksum  = cursor + NPAD;                    // 128
    int*   csr_src = blksum + 128;                     // 600064
    float* dinv    = (float*)(csr_src + 600064);       // NPAD
    float* u0      = dinv + NPAD;                      // 4,000,000
    float* u1      = u0 + (size_t)N_NODES * N_CLASSES; // 4,000,000

    const int B = 256;
    const int gE = (N_EDGES + B - 1) / B;              // 2344
    const int gG = (4 * N_NODES + B - 1) / B;          // 1563 (4 threads/node)

    k_zero <<<(NPAD / 4 + B - 1) / B, B, 0, stream>>>((int4*)deg);
    k_count<<<gE, B, 0, stream>>>(edst, deg);
    k_scan1<<<SCAN_NBLK, B, 0, stream>>>(deg, row_ptr, blksum);
    k_scan2<<<SCAN_NBLK, B, 0, stream>>>(deg, row_ptr, cursor, dinv, blksum);
    k_fill <<<gE, B, 0, stream>>>(esrc, edst, cursor, csr_src);

    k_gemm<<<(N_NODES + 127) / 128, B, 0, stream>>>(x, W, dinv, u0);

    k_gather    <<<gG, B, 0, stream>>>(u0, u1, dinv, row_ptr, csr_src);
    k_gather_out<<<gG, B, 0, stream>>>(u1, out, dinv, row_ptr, csr_src, b);
}

// Round 8
// 157.960 us; speedup vs baseline: 1.3383x; 1.0034x over previous
//
#include <hip/hip_runtime.h>

#define N_NODES   100000
#define N_EDGES   600000
#define D_FEAT    128
#define N_CLASSES 40

#define NPAD      100352            // N_NODES padded to 1024 multiple
#define SCAN_NBLK (NPAD / 1024)     // 98

// ================= CSR build =================

__global__ void k_zero(int4* __restrict__ deg4) {
    int i = blockIdx.x * blockDim.x + threadIdx.x;
    if (i < NPAD / 4) deg4[i] = make_int4(0, 0, 0, 0);
}

__global__ void k_count(const int* __restrict__ edst, int* __restrict__ deg) {
    int e = blockIdx.x * blockDim.x + threadIdx.x;
    if (e < N_EDGES) atomicAdd(&deg[edst[e]], 1);
}

// phase 1: per-block exclusive scan (1024 elems/block), local prefixes -> row_ptr
__global__ __launch_bounds__(256) void k_scan1(const int* __restrict__ deg,
                                               int* __restrict__ row_ptr,
                                               int* __restrict__ blksum) {
    __shared__ int wsum[4];
    int t = threadIdx.x;
    int lane = t & 63, w = t >> 6;
    int base = blockIdx.x * 1024 + t * 4;
    int4 v = *(const int4*)(deg + base);
    int s0 = v.x, s1 = s0 + v.y, s2 = s1 + v.z, s3 = s2 + v.w;
    int inc = s3;
#pragma unroll
    for (int d = 1; d < 64; d <<= 1) {
        int y = __shfl_up(inc, d, 64);
        if (lane >= d) inc += y;
    }
    if (lane == 63) wsum[w] = inc;
    __syncthreads();
    int woff = 0;
#pragma unroll
    for (int j = 0; j < 3; ++j) woff += (j < w) ? wsum[j] : 0;
    int texcl = woff + inc - s3;
    int4 o;
    o.x = texcl;
    o.y = texcl + s0;
    o.z = texcl + s1;
    o.w = texcl + s2;
    *(int4*)(row_ptr + base) = o;
    if (t == 255) blksum[blockIdx.x] = woff + inc;   // block total
}

// phase 2: add block offsets in place; emit cursor + dinv
__global__ __launch_bounds__(256) void k_scan2(const int* __restrict__ deg,
                                               int* __restrict__ row_ptr,
                                               int* __restrict__ cursor,
                                               float* __restrict__ dinv,
                                               const int* __restrict__ blksum) {
    __shared__ int s[SCAN_NBLK];
    int t = threadIdx.x;
    int blk = blockIdx.x;
    if (t < SCAN_NBLK) s[t] = blksum[t];
    __syncthreads();
    int off = 0;
    for (int j = 0; j < blk; ++j) off += s[j];
    int base = blk * 1024 + t * 4;
    int4 v = *(int4*)(row_ptr + base);
    v.x += off; v.y += off; v.z += off; v.w += off;
    *(int4*)(row_ptr + base) = v;
    *(int4*)(cursor + base) = v;
    int4 d = *(const int4*)(deg + base);
    float4 di;
    di.x = rsqrtf((float)(d.x + 1));
    di.y = rsqrtf((float)(d.y + 1));
    di.z = rsqrtf((float)(d.z + 1));
    di.w = rsqrtf((float)(d.w + 1));
    *(float4*)(dinv + base) = di;
    // row_ptr[N_NODES] = 600000 falls out of the scan (deg padding is zero)
}

__global__ void k_fill(const int* __restrict__ esrc, const int* __restrict__ edst,
                       int* __restrict__ cursor, int* __restrict__ csr_src) {
    int e = blockIdx.x * blockDim.x + threadIdx.x;
    if (e < N_EDGES) {
        int d = edst[e];
        int pos = atomicAdd(&cursor[d], 1);
        csr_src[pos] = esrc[e];
    }
}

// ================= u0 = (x @ W^T) * dinv[node] =================
// 128 threads/block = 32 quads; each quad (4 threads, 10 classes each)
// computes 2 consecutive nodes -> 64 nodes/block, grid 1563 (~6 blocks/CU).
// d4 loop unrolled x4 with loads grouped first: 8 global float4 + 40 LDS
// reads in flight per macro-iter, then 320 FMAs -> latency hidden under
// previous macro-iter's FMA stream instead of exposed every iteration.

#define WROW 132

__global__ __launch_bounds__(128) void k_gemm(const float* __restrict__ x,
                                              const float* __restrict__ W,
                                              const float* __restrict__ dinv,
                                              float* __restrict__ y) {
    __shared__ float Wl[N_CLASSES][WROW];
    int t = threadIdx.x;

    for (int f = t; f < N_CLASSES * (D_FEAT / 4); f += 128) {
        int c = f >> 5, d4 = f & 31;
        float4 w = ((const float4*)W)[f];
        *(float4*)&Wl[c][d4 * 4] = w;
    }
    __syncthreads();

    int quad = t >> 2;                     // 0..31
    int sub  = t & 3;
    int c0   = sub * 10;
    int n0   = blockIdx.x * 64 + quad * 2; // N_NODES % 2 == 0: pair all-or-nothing
    if (n0 >= N_NODES) return;

    const float4* xp = (const float4*)(x + (size_t)n0 * D_FEAT);  // rows n0, n0+1

    float acc[2][10];
#pragma unroll
    for (int k = 0; k < 2; ++k)
#pragma unroll
        for (int j = 0; j < 10; ++j) acc[k][j] = 0.f;

    for (int d4 = 0; d4 < D_FEAT / 4; d4 += 4) {
        float4 xa[4], xb[4];
#pragma unroll
        for (int u = 0; u < 4; ++u) {
            xa[u] = xp[d4 + u];
            xb[u] = xp[32 + d4 + u];
        }
#pragma unroll
        for (int u = 0; u < 4; ++u) {
#pragma unroll
            for (int j = 0; j < 10; ++j) {
                float4 wv = *(const float4*)&Wl[c0 + j][(d4 + u) * 4];
                acc[0][j] += xa[u].x * wv.x + xa[u].y * wv.y + xa[u].z * wv.z + xa[u].w * wv.w;
                acc[1][j] += xb[u].x * wv.x + xb[u].y * wv.y + xb[u].z * wv.z + xb[u].w * wv.w;
            }
        }
    }

#pragma unroll
    for (int k = 0; k < 2; ++k) {
        float di = dinv[n0 + k];
        float* o = y + (size_t)(n0 + k) * N_CLASSES + c0;
#pragma unroll
        for (int j = 0; j < 10; ++j) o[j] = acc[k][j] * di;
    }
}

// ================= CSR gather propagation on u (4 threads/node) =================
// u_out[d] = dinv[d]^2 * ( u_in[d] + sum_{s in N(d)} u_in[s] )
// thread role: sub = feature half (bit0), par = edge parity (bit1).
// parity loop unrolled x2: two source rows (10 float4 loads) in flight.

__global__ __launch_bounds__(256) void k_gather(const float* __restrict__ yin,
                                                float* __restrict__ yout,
                                                const float* __restrict__ dinv,
                                                const int* __restrict__ row_ptr,
                                                const int* __restrict__ csr_src) {
    int t = blockIdx.x * blockDim.x + threadIdx.x;
    int i = t >> 2;
    if (i >= N_NODES) return;
    int sub = t & 1;
    int par = (t >> 1) & 1;
    const float4* yb = (const float4*)yin;

    float4 a0, a1, a2, a3, a4;
    if (par == 0) {
        const float4* self = yb + (size_t)i * 10 + sub * 5;
        a0 = self[0]; a1 = self[1]; a2 = self[2]; a3 = self[3]; a4 = self[4];
    } else {
        a0 = a1 = a2 = a3 = a4 = make_float4(0.f, 0.f, 0.f, 0.f);
    }

    int e = row_ptr[i] + par, end = row_ptr[i + 1];
    for (; e + 2 < end; e += 4) {
        int s0 = csr_src[e], s1 = csr_src[e + 2];
        const float4* p0 = yb + (size_t)s0 * 10 + sub * 5;
        const float4* p1 = yb + (size_t)s1 * 10 + sub * 5;
        float4 v00 = p0[0], v01 = p0[1], v02 = p0[2], v03 = p0[3], v04 = p0[4];
        float4 v10 = p1[0], v11 = p1[1], v12 = p1[2], v13 = p1[3], v14 = p1[4];
        a0.x += v00.x + v10.x; a0.y += v00.y + v10.y; a0.z += v00.z + v10.z; a0.w += v00.w + v10.w;
        a1.x += v01.x + v11.x; a1.y += v01.y + v11.y; a1.z += v01.z + v11.z; a1.w += v01.w + v11.w;
        a2.x += v02.x + v12.x; a2.y += v02.y + v12.y; a2.z += v02.z + v12.z; a2.w += v02.w + v12.w;
        a3.x += v03.x + v13.x; a3.y += v03.y + v13.y; a3.z += v03.z + v13.z; a3.w += v03.w + v13.w;
        a4.x += v04.x + v14.x; a4.y += v04.y + v14.y; a4.z += v04.z + v14.z; a4.w += v04.w + v14.w;
    }
    if (e < end) {
        int s = csr_src[e];
        const float4* p = yb + (size_t)s * 10 + sub * 5;
        float4 v0 = p[0], v1 = p[1], v2 = p[2], v3 = p[3], v4 = p[4];
        a0.x += v0.x; a0.y += v0.y; a0.z += v0.z; a0.w += v0.w;
        a1.x += v1.x; a1.y += v1.y; a1.z += v1.z; a1.w += v1.w;
        a2.x += v2.x; a2.y += v2.y; a2.z += v2.z; a2.w += v2.w;
        a3.x += v3.x; a3.y += v3.y; a3.z += v3.z; a3.w += v3.w;
        a4.x += v4.x; a4.y += v4.y; a4.z += v4.z; a4.w += v4.w;
    }

    // combine edge-parity partial sums (lanes differ in bit 1)
    a0.x += __shfl_xor(a0.x, 2); a0.y += __shfl_xor(a0.y, 2); a0.z += __shfl_xor(a0.z, 2); a0.w += __shfl_xor(a0.w, 2);
    a1.x += __shfl_xor(a1.x, 2); a1.y += __shfl_xor(a1.y, 2); a1.z += __shfl_xor(a1.z, 2); a1.w += __shfl_xor(a1.w, 2);
    a2.x += __shfl_xor(a2.x, 2); a2.y += __shfl_xor(a2.y, 2); a2.z += __shfl_xor(a2.z, 2); a2.w += __shfl_xor(a2.w, 2);
    a3.x += __shfl_xor(a3.x, 2); a3.y += __shfl_xor(a3.y, 2); a3.z += __shfl_xor(a3.z, 2); a3.w += __shfl_xor(a3.w, 2);
    a4.x += __shfl_xor(a4.x, 2); a4.y += __shfl_xor(a4.y, 2); a4.z += __shfl_xor(a4.z, 2); a4.w += __shfl_xor(a4.w, 2);

    if (par == 0) {
        float di = dinv[i];
        float s2 = di * di;
        float4* o = (float4*)yout + (size_t)i * 10 + sub * 5;
        o[0] = make_float4(a0.x * s2, a0.y * s2, a0.z * s2, a0.w * s2);
        o[1] = make_float4(a1.x * s2, a1.y * s2, a1.z * s2, a1.w * s2);
        o[2] = make_float4(a2.x * s2, a2.y * s2, a2.z * s2, a2.w * s2);
        o[3] = make_float4(a3.x * s2, a3.y * s2, a3.z * s2, a3.w * s2);
        o[4] = make_float4(a4.x * s2, a4.y * s2, a4.z * s2, a4.w * s2);
    }
}

// final round: logits = dinv[d]*v + b, then log_softmax
__global__ __launch_bounds__(256) void k_gather_out(const float* __restrict__ yin,
                                                    float* __restrict__ out,
                                                    const float* __restrict__ dinv,
                                                    const int* __restrict__ row_ptr,
                                                    const int* __restrict__ csr_src,
                                                    const float* __restrict__ bias) {
    int t = blockIdx.x * blockDim.x + threadIdx.x;
    int i = t >> 2;
    if (i >= N_NODES) return;
    int sub = t & 1;
    int par = (t >> 1) & 1;
    const float4* yb = (const float4*)yin;

    float4 a0, a1, a2, a3, a4;
    if (par == 0) {
        const float4* self = yb + (size_t)i * 10 + sub * 5;
        a0 = self[0]; a1 = self[1]; a2 = self[2]; a3 = self[3]; a4 = self[4];
    } else {
        a0 = a1 = a2 = a3 = a4 = make_float4(0.f, 0.f, 0.f, 0.f);
    }

    int e = row_ptr[i] + par, end = row_ptr[i + 1];
    for (; e + 2 < end; e += 4) {
        int s0 = csr_src[e], s1 = csr_src[e + 2];
        const float4* p0 = yb + (size_t)s0 * 10 + sub * 5;
        const float4* p1 = yb + (size_t)s1 * 10 + sub * 5;
        float4 v00 = p0[0], v01 = p0[1], v02 = p0[2], v03 = p0[3], v04 = p0[4];
        float4 v10 = p1[0], v11 = p1[1], v12 = p1[2], v13 = p1[3], v14 = p1[4];
        a0.x += v00.x + v10.x; a0.y += v00.y + v10.y; a0.z += v00.z + v10.z; a0.w += v00.w + v10.w;
        a1.x += v01.x + v11.x; a1.y += v01.y + v11.y; a1.z += v01.z + v11.z; a1.w += v01.w + v11.w;
        a2.x += v02.x + v12.x; a2.y += v02.y + v12.y; a2.z += v02.z + v12.z; a2.w += v02.w + v12.w;
        a3.x += v03.x + v13.x; a3.y += v03.y + v13.y; a3.z += v03.z + v13.z; a3.w += v03.w + v13.w;
        a4.x += v04.x + v14.x; a4.y += v04.y + v14.y; a4.z += v04.z + v14.z; a4.w += v04.w + v14.w;
    }
    if (e < end) {
        int s = csr_src[e];
        const float4* p = yb + (size_t)s * 10 + sub * 5;
        float4 v0 = p[0], v1 = p[1], v2 = p[2], v3 = p[3], v4 = p[4];
        a0.x += v0.x; a0.y += v0.y; a0.z += v0.z; a0.w += v0.w;
        a1.x += v1.x; a1.y += v1.y; a1.z += v1.z; a1.w += v1.w;
        a2.x += v2.x; a2.y += v2.y; a2.z += v2.z; a2.w += v2.w;
        a3.x += v3.x; a3.y += v3.y; a3.z += v3.z; a3.w += v3.w;
        a4.x += v4.x; a4.y += v4.y; a4.z += v4.z; a4.w += v4.w;
    }

    a0.x += __shfl_xor(a0.x, 2); a0.y += __shfl_xor(a0.y, 2); a0.z += __shfl_xor(a0.z, 2); a0.w += __shfl_xor(a0.w, 2);
    a1.x += __shfl_xor(a1.x, 2); a1.y += __shfl_xor(a1.y, 2); a1.z += __shfl_xor(a1.z, 2); a1.w += __shfl_xor(a1.w, 2);
    a2.x += __shfl_xor(a2.x, 2); a2.y += __shfl_xor(a2.y, 2); a2.z += __shfl_xor(a2.z, 2); a2.w += __shfl_xor(a2.w, 2);
    a3.x += __shfl_xor(a3.x, 2); a3.y += __shfl_xor(a3.y, 2); a3.z += __shfl_xor(a3.z, 2); a3.w += __shfl_xor(a3.w, 2);
    a4.x += __shfl_xor(a4.x, 2); a4.y += __shfl_xor(a4.y, 2); a4.z += __shfl_xor(a4.z, 2); a4.w += __shfl_xor(a4.w, 2);

    float di = dinv[i];
    const float4* b4 = (const float4*)bias + sub * 5;
    float4 av[5] = {a0, a1, a2, a3, a4};
    float4 l[5];
    float m = -INFINITY;
#pragma unroll
    for (int r = 0; r < 5; ++r) {
        float4 b = b4[r];
        l[r].x = av[r].x * di + b.x;
        l[r].y = av[r].y * di + b.y;
        l[r].z = av[r].z * di + b.z;
        l[r].w = av[r].w * di + b.w;
        m = fmaxf(m, fmaxf(fmaxf(l[r].x, l[r].y), fmaxf(l[r].z, l[r].w)));
    }
    m = fmaxf(m, __shfl_xor(m, 1));     // combine feature halves (bit 0)
    float s = 0.f;
#pragma unroll
    for (int r = 0; r < 5; ++r) {
        s += __expf(l[r].x - m) + __expf(l[r].y - m)
           + __expf(l[r].z - m) + __expf(l[r].w - m);
    }
    s += __shfl_xor(s, 1);
    float lse = __logf(s) + m;

    if (par == 0) {
        float4* o = (float4*)out + (size_t)i * 10 + sub * 5;
#pragma unroll
        for (int r = 0; r < 5; ++r) {
            o[r] = make_float4(l[r].x - lse, l[r].y - lse, l[r].z - lse, l[r].w - lse);
        }
    }
}

// ================= launch =================

extern "C" void kernel_launch(void* const* d_in, const int* in_sizes, int n_in,
                              void* d_out, int out_size, void* d_ws, size_t ws_size,
                              hipStream_t stream) {
    const float* x   = (const float*)d_in[0];
    const int*   ei  = (const int*)d_in[1];
    const float* W   = (const float*)d_in[2];
    const float* b   = (const float*)d_in[3];
    float*       out = (float*)d_out;

    const int* esrc = ei;
    const int* edst = ei + N_EDGES;

    // workspace layout (4-byte elems, 16B-aligned sections)
    int*   deg     = (int*)d_ws;                       // NPAD
    int*   row_ptr = deg + NPAD;                       // NPAD (covers N_NODES+1)
    int*   cursor  = row_ptr + NPAD;                   // NPAD
    int*   blksum  = cursor + NPAD;                    // 128
    int*   csr_src = blksum + 128;                     // 600064
    float* dinv    = (float*)(csr_src + 600064);       // NPAD
    float* u0      = dinv + NPAD;                      // 4,000,000
    float* u1      = u0 + (size_t)N_NODES * N_CLASSES; // 4,000,000

    const int B = 256;
    const int gE = (N_EDGES + B - 1) / B;              // 2344
    const int gG = (4 * N_NODES + B - 1) / B;          // 1563 (4 threads/node)

    k_zero <<<(NPAD / 4 + B - 1) / B, B, 0, stream>>>((int4*)deg);
    k_count<<<gE, B, 0, stream>>>(edst, deg);
    k_scan1<<<SCAN_NBLK, B, 0, stream>>>(deg, row_ptr, blksum);
    k_scan2<<<SCAN_NBLK, B, 0, stream>>>(deg, row_ptr, cursor, dinv, blksum);
    k_fill <<<gE, B, 0, stream>>>(esrc, edst, cursor, csr_src);

    k_gemm<<<(N_NODES + 63) / 64, 128, 0, stream>>>(x, W, dinv, u0);

    k_gather    <<<gG, B, 0, stream>>>(u0, u1, dinv, row_ptr, csr_src);
    k_gather_out<<<gG, B, 0, stream>>>(u1, out, dinv, row_ptr, csr_src, b);
}